// Round 1
// baseline (182.041 us; speedup 1.0000x reference)
//
#include <hip/hip_runtime.h>
#include <stdint.h>

// FSUMGUCell: hy = (1-fg)*ng + fg*hx
//   fg = ( [hx|x]@w_f^T + b_f + 1 ) * 0.5
//   ng =   [fg*hx|x]@w_n^T + b_n
// B=H=I=2048, K=H+I=4096. bf16 MFMA path (threshold is 8x bf16-eps).
//
// Workspace layout (needs 67.1 MB):
//   A1 [2048][4096] bf16  = [hx|x]
//   A2 [2048][4096] bf16  = [fg*hx|x]  (first half filled by GEMM1 epilogue)
//   Wf [2048][4096] bf16
//   Wn [2048][4096] bf16
// fg (fp32) is staged in d_out between GEMM1 and GEMM2 (GEMM2 reads it, then
// overwrites the same index with hy -> safe, deterministic).

#define Hdim 2048
#define Idim 2048
#define Bdim 2048
#define Ktot 4096

typedef __bf16 bf16;
typedef __bf16 bf16x8 __attribute__((ext_vector_type(8)));
typedef float  f32x4  __attribute__((ext_vector_type(4)));

__device__ __forceinline__ void gload_lds16(const bf16* g, bf16* l) {
  __builtin_amdgcn_global_load_lds(
      (const __attribute__((address_space(1))) unsigned int*)g,
      (__attribute__((address_space(3))) unsigned int*)l,
      16, 0, 0);
}

// ---- prep: f32 -> bf16 conversion (vectorized x8) ----
__global__ void cvt_kernel(const float* __restrict__ src, bf16* __restrict__ dst, int n8) {
  int stride = gridDim.x * blockDim.x;
  for (int i = blockIdx.x * blockDim.x + threadIdx.x; i < n8; i += stride) {
    const float4* s = (const float4*)src + (size_t)i * 2;
    float4 a = s[0], b = s[1];
    bf16x8 o;
    o[0]=(bf16)a.x; o[1]=(bf16)a.y; o[2]=(bf16)a.z; o[3]=(bf16)a.w;
    o[4]=(bf16)b.x; o[5]=(bf16)b.y; o[6]=(bf16)b.z; o[7]=(bf16)b.w;
    *((bf16x8*)dst + i) = o;
  }
}

// ---- prep: A1 = [hx | x] bf16; A2 right half = x bf16 ----
__global__ void build_a_kernel(const float* __restrict__ hx, const float* __restrict__ x,
                               bf16* __restrict__ A1, bf16* __restrict__ A2) {
  int stride = gridDim.x * blockDim.x;
  const int n8 = Bdim * Ktot / 8;
  for (int i = blockIdx.x * blockDim.x + threadIdx.x; i < n8; i += stride) {
    int e = i * 8;
    int b = e >> 12;            // / 4096
    int k = e & (Ktot - 1);
    const float* src = (k < Hdim) ? (hx + (size_t)b * Hdim + k)
                                  : (x  + (size_t)b * Idim + (k - Hdim));
    const float4* s = (const float4*)src;
    float4 va = s[0], vb = s[1];
    bf16x8 o;
    o[0]=(bf16)va.x; o[1]=(bf16)va.y; o[2]=(bf16)va.z; o[3]=(bf16)va.w;
    o[4]=(bf16)vb.x; o[5]=(bf16)vb.y; o[6]=(bf16)vb.z; o[7]=(bf16)vb.w;
    *((bf16x8*)A1 + i) = o;
    if (k >= Hdim) *((bf16x8*)A2 + i) = o;
  }
}

// ---- m97-style 128x128 GEMM, BK=64, 4 waves, fused epilogue ----
// A [2048][4096] bf16 row-major, W [2048][4096] bf16 row-major (= B^T layout).
// C[row][col] = sum_k A[row][k] * W[col][k].
// LDS tiles [128][64] bf16, XOR-swizzled 16B chunks: LDS[row][c] holds
// global chunk c ^ (row&7)  (staged via inverse-swizzled global source,
// since global_load_lds writes linearly; read side applies the same XOR).
template<int EPI>
__global__ __launch_bounds__(256)
void gemm_kernel(const bf16* __restrict__ A, const bf16* __restrict__ W,
                 const float* __restrict__ bias,
                 const float* __restrict__ hx,
                 float* __restrict__ FG,       // EPI0: write fg ; EPI1: read fg
                 bf16* __restrict__ A2,        // EPI0: write bf16(fg*hx) left half
                 float* __restrict__ OUT)      // EPI1: write hy
{
  __shared__ bf16 ldsA[128 * 64];
  __shared__ bf16 ldsB[128 * 64];

  int bid  = blockIdx.x;
  int sbid = (bid & 7) * 32 + (bid >> 3);   // XCD swizzle (256 % 8 == 0, bijective)
  int tm = sbid >> 4, tn = sbid & 15;

  int tid  = threadIdx.x;
  int wave = tid >> 6, lane = tid & 63;
  int wr = (wave >> 1) * 64;   // wave row offset in tile
  int wc = (wave & 1) * 64;    // wave col offset
  int fr = lane & 15, fq = lane >> 4;
  int swz = fr & 7;            // row&7 == fr&7 for all fragment rows (16 | m-offset)

  int srow   = lane >> 3;                 // 0..7 within 8-row stage chunk
  int schunk = (lane & 7) ^ srow;         // inverse-swizzled global 16B chunk

  const bf16* gA = A + ((size_t)tm * 128) * Ktot + schunk * 8;
  const bf16* gB = W + ((size_t)tn * 128) * Ktot + schunk * 8;

  f32x4 acc[4][4] = {};

  for (int k0 = 0; k0 < Ktot; k0 += 64) {
    #pragma unroll
    for (int c4 = 0; c4 < 4; ++c4) {
      int c = wave * 4 + c4;              // 16 chunks of 8 rows
      int row = c * 8 + srow;
      gload_lds16(gA + (size_t)row * Ktot + k0, &ldsA[c * 512]);
      gload_lds16(gB + (size_t)row * Ktot + k0, &ldsB[c * 512]);
    }
    __syncthreads();                      // drains vmcnt before barrier (m97 structure)
    #pragma unroll
    for (int kk = 0; kk < 2; ++kk) {
      bf16x8 af[4], bv[4];
      #pragma unroll
      for (int m = 0; m < 4; ++m) {
        int row = wr + m * 16 + fr;
        int chunk = (kk * 4 + fq) ^ swz;
        af[m] = *(const bf16x8*)&ldsA[row * 64 + chunk * 8];
      }
      #pragma unroll
      for (int n = 0; n < 4; ++n) {
        int row = wc + n * 16 + fr;
        int chunk = (kk * 4 + fq) ^ swz;
        bv[n] = *(const bf16x8*)&ldsB[row * 64 + chunk * 8];
      }
      #pragma unroll
      for (int m = 0; m < 4; ++m)
        #pragma unroll
        for (int n = 0; n < 4; ++n)
          acc[m][n] = __builtin_amdgcn_mfma_f32_16x16x32_bf16(af[m], bv[n], acc[m][n], 0, 0, 0);
    }
    __syncthreads();
  }

  // epilogue: C/D layout col = lane&15, row = (lane>>4)*4 + i  [m89 verified]
  int row0 = tm * 128 + wr + fq * 4;
  int col0 = tn * 128 + wc + fr;
  #pragma unroll
  for (int n = 0; n < 4; ++n) {
    int gcol = col0 + n * 16;
    float bv = bias[gcol];
    #pragma unroll
    for (int m = 0; m < 4; ++m) {
      #pragma unroll
      for (int i = 0; i < 4; ++i) {
        int grow = row0 + m * 16 + i;
        size_t idx = (size_t)grow * Hdim + gcol;
        float v = acc[m][n][i] + bv;
        if (EPI == 0) {
          float fg   = (v + 1.0f) * 0.5f;
          float fghx = fg * hx[idx];
          FG[idx] = fg;                                  // fp32 fg staged in d_out
          A2[(size_t)grow * Ktot + gcol] = (bf16)fghx;   // GEMM2 A-operand, left half
        } else {
          float fg   = FG[idx];                          // read before overwrite
          float fghx = fg * hx[idx];                     // fp32 recompute (accuracy)
          OUT[idx] = v - fg * v + fghx;                  // (1-fg)*ng + fg*hx
        }
      }
    }
  }
}

extern "C" void kernel_launch(void* const* d_in, const int* in_sizes, int n_in,
                              void* d_out, int out_size, void* d_ws, size_t ws_size,
                              hipStream_t stream) {
  const float* x   = (const float*)d_in[0];
  const float* hx  = (const float*)d_in[1];
  const float* w_f = (const float*)d_in[2];
  const float* b_f = (const float*)d_in[3];
  const float* w_n = (const float*)d_in[4];
  const float* b_n = (const float*)d_in[5];
  float* out = (float*)d_out;

  bf16* A1 = (bf16*)d_ws;
  bf16* A2 = A1 + (size_t)Bdim * Ktot;
  bf16* Wf = A2 + (size_t)Bdim * Ktot;
  bf16* Wn = Wf + (size_t)Hdim * Ktot;
  // total ws use: 4 * 16.78 MB = 67.1 MB

  const int n8w = Hdim * Ktot / 8;
  cvt_kernel<<<1024, 256, 0, stream>>>(w_f, Wf, n8w);
  cvt_kernel<<<1024, 256, 0, stream>>>(w_n, Wn, n8w);
  build_a_kernel<<<1024, 256, 0, stream>>>(hx, x, A1, A2);

  // GEMM1: fg path. fg (fp32) staged in d_out; bf16(fg*hx) -> A2 left half.
  gemm_kernel<0><<<256, 256, 0, stream>>>(A1, Wf, b_f, hx, out, A2, nullptr);
  // GEMM2: ng path + final hy into d_out (reads fg from d_out first).
  gemm_kernel<1><<<256, 256, 0, stream>>>(A2, Wn, b_n, hx, out, nullptr, out);
}

// Round 2
// 151.960 us; speedup vs baseline: 1.1980x; 1.1980x over previous
//
#include <hip/hip_runtime.h>
#include <stdint.h>

// FSUMGUCell: hy = (1-fg)*ng + fg*hx
//   fg = ( [hx|x]@w_f^T + b_f + 1 ) * 0.5
//   ng =   [fg*hx|x]@w_n^T + b_n
// B=H=I=2048, K=H+I=4096. bf16 MFMA path.
//
// Round 2: 8-wave 128x128 tile, double-buffered LDS, counted vmcnt(4)
// prefetch (T3/T4 minimum 2-phase). Raw s_barrier (no __syncthreads — its
// implicit vmcnt(0) was the round-1 serializer at 1 block/CU).

#define Hdim 2048
#define Idim 2048
#define Bdim 2048
#define Ktot 4096

typedef __bf16 bf16;
typedef __bf16 bf16x8 __attribute__((ext_vector_type(8)));
typedef float  f32x4  __attribute__((ext_vector_type(4)));

__device__ __forceinline__ void gload_lds16(const bf16* g, bf16* l) {
  __builtin_amdgcn_global_load_lds(
      (const __attribute__((address_space(1))) unsigned int*)g,
      (__attribute__((address_space(3))) unsigned int*)l,
      16, 0, 0);
}

// ---- prep: f32 -> bf16 conversion (vectorized x8) ----
__global__ void cvt_kernel(const float* __restrict__ src, bf16* __restrict__ dst, int n8) {
  int stride = gridDim.x * blockDim.x;
  for (int i = blockIdx.x * blockDim.x + threadIdx.x; i < n8; i += stride) {
    const float4* s = (const float4*)src + (size_t)i * 2;
    float4 a = s[0], b = s[1];
    bf16x8 o;
    o[0]=(bf16)a.x; o[1]=(bf16)a.y; o[2]=(bf16)a.z; o[3]=(bf16)a.w;
    o[4]=(bf16)b.x; o[5]=(bf16)b.y; o[6]=(bf16)b.z; o[7]=(bf16)b.w;
    *((bf16x8*)dst + i) = o;
  }
}

// ---- prep: A1 = [hx | x] bf16; A2 right half = x bf16 ----
__global__ void build_a_kernel(const float* __restrict__ hx, const float* __restrict__ x,
                               bf16* __restrict__ A1, bf16* __restrict__ A2) {
  int stride = gridDim.x * blockDim.x;
  const int n8 = Bdim * Ktot / 8;
  for (int i = blockIdx.x * blockDim.x + threadIdx.x; i < n8; i += stride) {
    int e = i * 8;
    int b = e >> 12;            // / 4096
    int k = e & (Ktot - 1);
    const float* src = (k < Hdim) ? (hx + (size_t)b * Hdim + k)
                                  : (x  + (size_t)b * Idim + (k - Hdim));
    const float4* s = (const float4*)src;
    float4 va = s[0], vb = s[1];
    bf16x8 o;
    o[0]=(bf16)va.x; o[1]=(bf16)va.y; o[2]=(bf16)va.z; o[3]=(bf16)va.w;
    o[4]=(bf16)vb.x; o[5]=(bf16)vb.y; o[6]=(bf16)vb.z; o[7]=(bf16)vb.w;
    *((bf16x8*)A1 + i) = o;
    if (k >= Hdim) *((bf16x8*)A2 + i) = o;
  }
}

// ---- 128x128 GEMM, BK=64, 8 waves, dbuf LDS + counted vmcnt, fused epi ----
// A [2048][4096] bf16 rm, W [2048][4096] bf16 rm (= B^T layout).
// C[row][col] = sum_k A[row][k] * W[col][k].
// LDS tile [128][64] bf16 per buffer; 16B-chunk XOR swizzle: LDS[row][s]
// holds global chunk s ^ (row&7), staged via inverse-swizzled global source
// (global_load_lds writes linearly), read with the same XOR.
template<int EPI>
__global__ __launch_bounds__(512)
void gemm_kernel(const bf16* __restrict__ A, const bf16* __restrict__ W,
                 const float* __restrict__ bias,
                 const float* __restrict__ hx,
                 float* __restrict__ FG,       // EPI0: write fg ; EPI1: read fg
                 bf16* __restrict__ A2,        // EPI0: write bf16(fg*hx) left half
                 float* __restrict__ OUT)      // EPI1: write hy
{
  __shared__ bf16 ldsA[2 * 128 * 64];
  __shared__ bf16 ldsB[2 * 128 * 64];

  int bid  = blockIdx.x;
  int sbid = (bid & 7) * 32 + (bid >> 3);   // XCD swizzle (256%8==0, bijective)
  int tm = sbid >> 4, tn = sbid & 15;

  int tid  = threadIdx.x;
  int w = tid >> 6, lane = tid & 63;
  int wrow = (w >> 2) * 64;    // 2x4 wave grid: 64 rows x 32 cols per wave
  int wcol = (w & 3) * 32;
  int fr = lane & 15, fq = lane >> 4;
  int swz = fr & 7;

  // staging: 1024 16B chunks per tile; thread t covers chunks {t, t+512}.
  int srow = w * 8 + (lane >> 3);             // row for chunk t (0..63)
  int co   = ((lane & 7) ^ (lane >> 3)) * 8;  // inverse-swizzled k-chunk
  const bf16* pA0 = A + (size_t)(tm * 128 + srow) * Ktot + co;
  const bf16* pB0 = W + (size_t)(tn * 128 + srow) * Ktot + co;
  const size_t rowskip = (size_t)64 * Ktot;   // chunk t+512 -> row +64
  int lb = w * 512;                            // wave-uniform LDS elem base

#define STAGE(buf, koff) do {                                            \
    gload_lds16(pA0 + (koff),           &ldsA[(buf)*8192 + lb]);         \
    gload_lds16(pA0 + rowskip + (koff), &ldsA[(buf)*8192 + 4096 + lb]);  \
    gload_lds16(pB0 + (koff),           &ldsB[(buf)*8192 + lb]);         \
    gload_lds16(pB0 + rowskip + (koff), &ldsB[(buf)*8192 + 4096 + lb]);  \
  } while (0)

  f32x4 acc[4][2] = {};

  auto compute = [&](int buf) {
    #pragma unroll
    for (int kk = 0; kk < 2; ++kk) {
      bf16x8 af[4], bv[2];
      int ch = (kk * 4 + fq) ^ swz;
      #pragma unroll
      for (int m = 0; m < 4; ++m) {
        int row = wrow + m * 16 + fr;
        af[m] = *(const bf16x8*)&ldsA[buf * 8192 + row * 64 + ch * 8];
      }
      #pragma unroll
      for (int n = 0; n < 2; ++n) {
        int row = wcol + n * 16 + fr;
        bv[n] = *(const bf16x8*)&ldsB[buf * 8192 + row * 64 + ch * 8];
      }
      #pragma unroll
      for (int m = 0; m < 4; ++m)
        #pragma unroll
        for (int n = 0; n < 2; ++n)
          acc[m][n] = __builtin_amdgcn_mfma_f32_16x16x32_bf16(af[m], bv[n], acc[m][n], 0, 0, 0);
    }
  };

  STAGE(0, 0);
  int cur = 0;
  for (int t = 0; t < Ktot / 64 - 1; ++t) {
    STAGE(cur ^ 1, (t + 1) * 64);                      // prefetch next K-tile
    asm volatile("s_waitcnt vmcnt(4)" ::: "memory");   // cur's 4 done; next's 4 in flight
    __builtin_amdgcn_s_barrier();
    compute(cur);
    __builtin_amdgcn_s_barrier();                      // reads done -> buf reusable
    cur ^= 1;
  }
  asm volatile("s_waitcnt vmcnt(0)" ::: "memory");
  __builtin_amdgcn_s_barrier();
  compute(cur);
#undef STAGE

  // epilogue: C/D layout col = lane&15, row = (lane>>4)*4 + i  [m89 verified]
  int row0 = tm * 128 + wrow + fq * 4;
  int col0 = tn * 128 + wcol + fr;
  #pragma unroll
  for (int n = 0; n < 2; ++n) {
    int gcol = col0 + n * 16;
    float bv = bias[gcol];
    #pragma unroll
    for (int m = 0; m < 4; ++m) {
      #pragma unroll
      for (int i = 0; i < 4; ++i) {
        int grow = row0 + m * 16 + i;
        size_t idx = (size_t)grow * Hdim + gcol;
        float v = acc[m][n][i] + bv;
        if (EPI == 0) {
          float fg   = (v + 1.0f) * 0.5f;
          float fghx = fg * hx[idx];
          FG[idx] = fg;                                  // fp32 fg staged in d_out
          A2[(size_t)grow * Ktot + gcol] = (bf16)fghx;   // GEMM2 A-operand, left half
        } else {
          float fg   = FG[idx];                          // read before overwrite
          float fghx = fg * hx[idx];                     // fp32 recompute (accuracy)
          OUT[idx] = v - fg * v + fghx;                  // (1-fg)*ng + fg*hx
        }
      }
    }
  }
}

extern "C" void kernel_launch(void* const* d_in, const int* in_sizes, int n_in,
                              void* d_out, int out_size, void* d_ws, size_t ws_size,
                              hipStream_t stream) {
  const float* x   = (const float*)d_in[0];
  const float* hx  = (const float*)d_in[1];
  const float* w_f = (const float*)d_in[2];
  const float* b_f = (const float*)d_in[3];
  const float* w_n = (const float*)d_in[4];
  const float* b_n = (const float*)d_in[5];
  float* out = (float*)d_out;

  bf16* A1 = (bf16*)d_ws;
  bf16* A2 = A1 + (size_t)Bdim * Ktot;
  bf16* Wf = A2 + (size_t)Bdim * Ktot;
  bf16* Wn = Wf + (size_t)Hdim * Ktot;
  // total ws use: 4 * 16.78 MB = 67.1 MB

  const int n8w = Hdim * Ktot / 8;
  cvt_kernel<<<1024, 256, 0, stream>>>(w_f, Wf, n8w);
  cvt_kernel<<<1024, 256, 0, stream>>>(w_n, Wn, n8w);
  build_a_kernel<<<1024, 256, 0, stream>>>(hx, x, A1, A2);

  // GEMM1: fg path. fg (fp32) staged in d_out; bf16(fg*hx) -> A2 left half.
  gemm_kernel<0><<<256, 512, 0, stream>>>(A1, Wf, b_f, hx, out, A2, nullptr);
  // GEMM2: ng path + final hy into d_out (reads fg from d_out first).
  gemm_kernel<1><<<256, 512, 0, stream>>>(A2, Wn, b_n, hx, out, nullptr, out);
}

// Round 3
// 116.861 us; speedup vs baseline: 1.5578x; 1.3003x over previous
//
#include <hip/hip_runtime.h>
#include <stdint.h>

// FSUMGUCell: hy = (1-fg)*ng + fg*hx
//   fg = ( [hx|x]@w_f^T + b_f + 1 ) * 0.5
//   ng =   [fg*hx|x]@w_n^T + b_n
// B=H=I=2048, K=H+I=4096. bf16 MFMA path.
//
// Round 3: in-block split-K. 8 waves = 2 K-groups x 4 waves; each wave owns a
// 64x64 output sub-tile (4x4 frags -> 1.5x fewer LDS reads than round 2's
// 64x32). Each group: own dbuf LDS tiles (total 128 KB), counted vmcnt(8).
// Group-1 partials summed into group-0 via LDS; epilogue stays fused.

#define Hdim 2048
#define Idim 2048
#define Bdim 2048
#define Ktot 4096
#define KHALF 2048
#define NSTEP (KHALF / 64)

typedef __bf16 bf16;
typedef __bf16 bf16x8 __attribute__((ext_vector_type(8)));
typedef float  f32x4  __attribute__((ext_vector_type(4)));

__device__ __forceinline__ void gload_lds16(const bf16* g, bf16* l) {
  __builtin_amdgcn_global_load_lds(
      (const __attribute__((address_space(1))) unsigned int*)g,
      (__attribute__((address_space(3))) unsigned int*)l,
      16, 0, 0);
}

// ---- prep: f32 -> bf16 conversion (vectorized x8) ----
__global__ void cvt_kernel(const float* __restrict__ src, bf16* __restrict__ dst, int n8) {
  int stride = gridDim.x * blockDim.x;
  for (int i = blockIdx.x * blockDim.x + threadIdx.x; i < n8; i += stride) {
    const float4* s = (const float4*)src + (size_t)i * 2;
    float4 a = s[0], b = s[1];
    bf16x8 o;
    o[0]=(bf16)a.x; o[1]=(bf16)a.y; o[2]=(bf16)a.z; o[3]=(bf16)a.w;
    o[4]=(bf16)b.x; o[5]=(bf16)b.y; o[6]=(bf16)b.z; o[7]=(bf16)b.w;
    *((bf16x8*)dst + i) = o;
  }
}

// ---- prep: A1 = [hx | x] bf16; A2 right half = x bf16 ----
__global__ void build_a_kernel(const float* __restrict__ hx, const float* __restrict__ x,
                               bf16* __restrict__ A1, bf16* __restrict__ A2) {
  int stride = gridDim.x * blockDim.x;
  const int n8 = Bdim * Ktot / 8;
  for (int i = blockIdx.x * blockDim.x + threadIdx.x; i < n8; i += stride) {
    int e = i * 8;
    int b = e >> 12;            // / 4096
    int k = e & (Ktot - 1);
    const float* src = (k < Hdim) ? (hx + (size_t)b * Hdim + k)
                                  : (x  + (size_t)b * Idim + (k - Hdim));
    const float4* s = (const float4*)src;
    float4 va = s[0], vb = s[1];
    bf16x8 o;
    o[0]=(bf16)va.x; o[1]=(bf16)va.y; o[2]=(bf16)va.z; o[3]=(bf16)va.w;
    o[4]=(bf16)vb.x; o[5]=(bf16)vb.y; o[6]=(bf16)vb.z; o[7]=(bf16)vb.w;
    *((bf16x8*)A1 + i) = o;
    if (k >= Hdim) *((bf16x8*)A2 + i) = o;
  }
}

// ---- 128x128 GEMM, split-K in-block, 8 waves, dbuf + counted vmcnt ----
// A [2048][4096] bf16 rm, W [2048][4096] bf16 rm (= B^T layout).
// C[row][col] = sum_k A[row][k] * W[col][k].
// Per group: LDS tiles [128][64] bf16 x2 bufs; 16B-chunk XOR swizzle
// (LDS[row][c] holds global chunk c ^ (row&7); staged via inverse-swizzled
// global source since global_load_lds writes linearly; read applies same XOR).
template<int EPI>
__global__ __launch_bounds__(512)
void gemm_kernel(const bf16* __restrict__ A, const bf16* __restrict__ W,
                 const float* __restrict__ bias,
                 const float* __restrict__ hx,
                 float* __restrict__ FG,       // EPI0: write fg ; EPI1: read fg
                 bf16* __restrict__ A2,        // EPI0: write bf16(fg*hx) left half
                 float* __restrict__ OUT)      // EPI1: write hy
{
  __shared__ bf16 lds[2][2][2][8192];   // [group][buf][A=0/B=1][128*64] = 128 KB

  int bid  = blockIdx.x;
  int sbid = (bid & 7) * 32 + (bid >> 3);   // XCD swizzle (256%8==0, bijective)
  int tm = sbid >> 4, tn = sbid & 15;

  int tid  = threadIdx.x;
  int w = tid >> 6, lane = tid & 63;
  int g = w >> 2, sub = w & 3;
  int wrow = (sub >> 1) * 64;   // 2x2 wave grid within tile: 64x64 per wave
  int wcol = (sub & 1) * 64;
  int fr = lane & 15, fq = lane >> 4;
  int swz = fr & 7;

  // staging: per group-step 2048 16B chunks (A 1024 + B 1024), 256 threads ->
  // 8 loads/thread. Thread gtid, pass j: row = j*32 + (gtid>>3), dest chunk
  // gtid&7, source chunk (gtid&7)^(row&7) (inverse swizzle).
  int gtid = sub * 64 + lane;
  int srow = gtid >> 3;
  int csrc = (gtid & 7) ^ (srow & 7);
  const bf16* pA = A + (size_t)(tm * 128 + srow) * Ktot + csrc * 8 + g * KHALF;
  const bf16* pB = W + (size_t)(tn * 128 + srow) * Ktot + csrc * 8 + g * KHALF;
  int lbase = sub * 512;                     // + j*2048 ; gload adds lane*16B

#define STAGE(buf, koff) do {                                                      \
    _Pragma("unroll")                                                              \
    for (int j = 0; j < 4; ++j) {                                                  \
      gload_lds16(pA + (size_t)j * 32 * Ktot + (koff), &lds[g][buf][0][j * 2048 + lbase]); \
      gload_lds16(pB + (size_t)j * 32 * Ktot + (koff), &lds[g][buf][1][j * 2048 + lbase]); \
    }                                                                              \
  } while (0)

  f32x4 acc[4][4] = {};

  auto compute = [&](int buf) {
    #pragma unroll
    for (int kk = 0; kk < 2; ++kk) {
      bf16x8 af[4], bv[4];
      int ch = ((kk * 4 + fq) ^ swz) * 8;
      #pragma unroll
      for (int m = 0; m < 4; ++m)
        af[m] = *(const bf16x8*)&lds[g][buf][0][(wrow + m * 16 + fr) * 64 + ch];
      #pragma unroll
      for (int n = 0; n < 4; ++n)
        bv[n] = *(const bf16x8*)&lds[g][buf][1][(wcol + n * 16 + fr) * 64 + ch];
      #pragma unroll
      for (int m = 0; m < 4; ++m)
        #pragma unroll
        for (int n = 0; n < 4; ++n)
          acc[m][n] = __builtin_amdgcn_mfma_f32_16x16x32_bf16(af[m], bv[n], acc[m][n], 0, 0, 0);
    }
  };

  STAGE(0, 0);
  int cur = 0;
  for (int t = 0; t < NSTEP - 1; ++t) {
    STAGE(cur ^ 1, (t + 1) * 64);                      // prefetch next K-tile
    asm volatile("s_waitcnt vmcnt(8)" ::: "memory");   // cur's 8 done; next 8 in flight
    __builtin_amdgcn_s_barrier();
    compute(cur);
    __builtin_amdgcn_s_barrier();                      // reads done -> buf reusable
    cur ^= 1;
  }
  asm volatile("s_waitcnt vmcnt(0)" ::: "memory");
  __builtin_amdgcn_s_barrier();
  compute(cur);
#undef STAGE

  // ---- cross-group reduction via LDS (reuse tile space), fused epilogue ----
  __syncthreads();
  float* xch = (float*)&lds[0][0][0][0];    // 4 subs x 16 KB = 64 KB
  if (g == 1) {
    #pragma unroll
    for (int m = 0; m < 4; ++m)
      #pragma unroll
      for (int n = 0; n < 4; ++n)
        *(f32x4*)&xch[sub * 4096 + (m * 4 + n) * 256 + lane * 4] = acc[m][n];
  }
  __syncthreads();
  if (g == 0) {
    // C/D layout: col = lane&15, row = (lane>>4)*4 + i  [m89 verified]
    int row0 = tm * 128 + wrow + fq * 4;
    int col0 = tn * 128 + wcol + fr;
    #pragma unroll
    for (int n = 0; n < 4; ++n) {
      int gcol = col0 + n * 16;
      float bv = bias[gcol];
      #pragma unroll
      for (int m = 0; m < 4; ++m) {
        f32x4 part = *(const f32x4*)&xch[sub * 4096 + (m * 4 + n) * 256 + lane * 4];
        #pragma unroll
        for (int i = 0; i < 4; ++i) {
          int grow = row0 + m * 16 + i;
          size_t idx = (size_t)grow * Hdim + gcol;
          float v = acc[m][n][i] + part[i] + bv;
          if (EPI == 0) {
            float fg   = (v + 1.0f) * 0.5f;
            float fghx = fg * hx[idx];
            FG[idx] = fg;                                  // fp32 fg staged in d_out
            A2[(size_t)grow * Ktot + gcol] = (bf16)fghx;   // GEMM2 A-operand, left half
          } else {
            float fg   = FG[idx];                          // read before overwrite
            float fghx = fg * hx[idx];                     // fp32 recompute (accuracy)
            OUT[idx] = v - fg * v + fghx;                  // (1-fg)*ng + fg*hx
          }
        }
      }
    }
  }
}

extern "C" void kernel_launch(void* const* d_in, const int* in_sizes, int n_in,
                              void* d_out, int out_size, void* d_ws, size_t ws_size,
                              hipStream_t stream) {
  const float* x   = (const float*)d_in[0];
  const float* hx  = (const float*)d_in[1];
  const float* w_f = (const float*)d_in[2];
  const float* b_f = (const float*)d_in[3];
  const float* w_n = (const float*)d_in[4];
  const float* b_n = (const float*)d_in[5];
  float* out = (float*)d_out;

  bf16* A1 = (bf16*)d_ws;
  bf16* A2 = A1 + (size_t)Bdim * Ktot;
  bf16* Wf = A2 + (size_t)Bdim * Ktot;
  bf16* Wn = Wf + (size_t)Hdim * Ktot;
  // total ws use: 4 * 16.78 MB = 67.1 MB

  const int n8w = Hdim * Ktot / 8;
  cvt_kernel<<<1024, 256, 0, stream>>>(w_f, Wf, n8w);
  cvt_kernel<<<1024, 256, 0, stream>>>(w_n, Wn, n8w);
  build_a_kernel<<<1024, 256, 0, stream>>>(hx, x, A1, A2);

  // GEMM1: fg path. fg (fp32) staged in d_out; bf16(fg*hx) -> A2 left half.
  gemm_kernel<0><<<256, 512, 0, stream>>>(A1, Wf, b_f, hx, out, A2, nullptr);
  // GEMM2: ng path + final hy into d_out (reads fg from d_out first).
  gemm_kernel<1><<<256, 512, 0, stream>>>(A2, Wn, b_n, hx, out, nullptr, out);
}